// Round 1
// baseline (196.373 us; speedup 1.0000x reference)
//
#include <hip/hip_runtime.h>

// ---------------- helpers ----------------

typedef __bf16 bf16x8 __attribute__((ext_vector_type(8)));
typedef float  f32x4  __attribute__((ext_vector_type(4)));

__device__ __forceinline__ unsigned short f2bf(float x) {
    unsigned int u = __builtin_bit_cast(unsigned int, x);
    u = (u + 0x7fffu + ((u >> 16) & 1u)) >> 16;
    return (unsigned short)u;
}

__device__ __forceinline__ void gl2lds16(const unsigned short* g, unsigned short* l) {
    __builtin_amdgcn_global_load_lds(
        (const __attribute__((address_space(1))) unsigned int*)g,
        (__attribute__((address_space(3))) unsigned int*)l,
        16, 0, 0);
}

__device__ __forceinline__ float sigf(float x) {
    return __builtin_amdgcn_rcpf(1.f + __expf(-x));
}
__device__ __forceinline__ float tanh_fast(float x) {
    return 2.f * __builtin_amdgcn_rcpf(1.f + __expf(-2.f * x)) - 1.f;
}

// ---------------- conversion: activations -> bf16 A [4096][4096] ----------------
// columns: [0,1024)=top_buf, [1024,2048)=stack1, [2048,3072)=stack2, [3072,4096)=h_prev

__global__ void convert_A(const float* __restrict__ A0, const float* __restrict__ A1,
                          const float* __restrict__ A2, const float* __restrict__ A3,
                          unsigned short* __restrict__ Abf) {
    int idx = blockIdx.x * 256 + threadIdx.x;   // 4194304 threads, 4 elems each
    int e0  = idx * 4;
    int b   = e0 >> 12;
    int k   = e0 & 4095;
    const float* S = (k < 1024) ? A0 : (k < 2048) ? A1 : (k < 3072) ? A2 : A3;
    int col = k & 1023;
    const float4 v = *reinterpret_cast<const float4*>(S + (size_t)b * 1024 + col);
    ushort4 o;
    o.x = f2bf(v.x); o.y = f2bf(v.y); o.z = f2bf(v.z); o.w = f2bf(v.w);
    *reinterpret_cast<ushort4*>(Abf + (size_t)b * 4096 + k) = o;
}

// ---------------- conversion: weights -> bf16 B^T with gate-interleave permutation ----
// Bt[p][k] = Wcat[k][ g*1024 + n ],  p = (n>>5)*128 + ((n>>4)&1)*64 + g*16 + (n&15)
// so that in the GEMM epilogue, lane (l&15) holds gates a,i,f,o of one unit in ni=0..3.

__global__ void convert_B(const float* __restrict__ Wb, const float* __restrict__ W1,
                          const float* __restrict__ W2, const float* __restrict__ Wl,
                          unsigned short* __restrict__ Bt) {
    __shared__ float t[32][33];
    int tile = blockIdx.x;            // 128 j-tiles x 128 k-tiles
    int jt = tile & 127, kt = tile >> 7;
    int j0 = jt * 32, k0 = kt * 32;
    int ksel = k0 >> 10;
    const float* S = (ksel == 0) ? Wb : (ksel == 1) ? W1 : (ksel == 2) ? W2 : Wl;
    int kloc = k0 & 1023;
    int tx = threadIdx.x & 31, ty = threadIdx.x >> 5;   // ty in 0..7
#pragma unroll
    for (int i = 0; i < 4; ++i) {
        int r = ty + i * 8;
        t[r][tx] = S[(size_t)(kloc + r) * 4096 + j0 + tx];
    }
    __syncthreads();
    int g = j0 >> 10;
    int nbase = j0 & 1023;
#pragma unroll
    for (int i = 0; i < 4; ++i) {
        int jj = ty + i * 8;
        int n  = nbase + jj;
        int p  = (n >> 5) * 128 + ((n >> 4) & 1) * 64 + g * 16 + (n & 15);
        Bt[(size_t)p * 4096 + k0 + tx] = f2bf(t[tx][jj]);
    }
}

// ---------------- GEMM (m97 structure) + fused LSTM epilogue ----------------
// A [4096][4096] bf16 row-major, Bt [4096(p)][4096(k)] bf16 row-major.
// 128x128 tile, BK=32, 4 waves (2x2), each wave 64x64 = 4x4 frags of 16x16x32.

__global__ __launch_bounds__(256, 2) void gemm_lstm(
        const unsigned short* __restrict__ A,
        const unsigned short* __restrict__ Bt,
        const float* __restrict__ bias,
        const float* __restrict__ cprev,
        float* __restrict__ out) {
    __shared__ unsigned short As[128 * 32];   // 8 KB, [row][k]
    __shared__ unsigned short Bs[128 * 32];   // 8 KB, [p][k]

    const int tid  = threadIdx.x;
    const int wid  = tid >> 6;
    const int lane = tid & 63;
    const int wm = wid >> 1, wn = wid & 1;
    const int lr = lane & 15, lq = lane >> 4;
    const int bm = blockIdx.y, bc = blockIdx.x;

    f32x4 acc[4][4] = {};   // acc[mi][gate]

    // staging: wave wid covers rows [32*wid, 32*wid+32) of its tile, 2 chunks of 16 rows
    const int srow = 32 * wid + (lane >> 2);
    const int skof = (lane & 3) * 8;
    const unsigned short* pA0 = A  + (size_t)(bm * 128 + srow) * 4096 + skof;
    const unsigned short* pB0 = Bt + (size_t)(bc * 128 + srow) * 4096 + skof;
    unsigned short* lA = As + wid * 1024;   // wave-uniform LDS base (chunk = 1024 B = 512 elems x2)
    unsigned short* lB = Bs + wid * 1024;

    for (int k0 = 0; k0 < 4096; k0 += 32) {
        gl2lds16(pA0 + k0,             lA);
        gl2lds16(pA0 + 16 * 4096 + k0, lA + 512);
        gl2lds16(pB0 + k0,             lB);
        gl2lds16(pB0 + 16 * 4096 + k0, lB + 512);
        __syncthreads();   // drains vmcnt -> LDS tiles ready

        bf16x8 af[4], bfr[4];
#pragma unroll
        for (int mi = 0; mi < 4; ++mi)
            af[mi] = *reinterpret_cast<const bf16x8*>(As + (wm * 64 + mi * 16 + lr) * 32 + lq * 8);
#pragma unroll
        for (int ni = 0; ni < 4; ++ni)
            bfr[ni] = *reinterpret_cast<const bf16x8*>(Bs + (wn * 64 + ni * 16 + lr) * 32 + lq * 8);
#pragma unroll
        for (int mi = 0; mi < 4; ++mi)
#pragma unroll
            for (int ni = 0; ni < 4; ++ni)
                acc[mi][ni] = __builtin_amdgcn_mfma_f32_16x16x32_bf16(
                    af[mi], bfr[ni], acc[mi][ni], 0, 0, 0);
        __syncthreads();   // before overwriting LDS next iteration
    }

    // ---- fused LSTM epilogue: lane holds a,i,f,o of unit n in ni=0..3 ----
    const int n = bc * 32 + wn * 16 + lr;     // tracker unit, 0..1023
    const float ba = bias[n];
    const float bi = bias[1024 + n];
    const float bf_ = bias[2048 + n];
    const float bo = bias[3072 + n];
    float* outh = out;
    float* outc = out + (size_t)4096 * 1024;

#pragma unroll
    for (int mi = 0; mi < 4; ++mi) {
        const int row0 = bm * 128 + wm * 64 + mi * 16 + lq * 4;
#pragma unroll
        for (int r = 0; r < 4; ++r) {
            const int gm = row0 + r;
            const size_t off = (size_t)gm * 1024 + n;
            const float a  = acc[mi][0][r] + ba;
            const float ii = acc[mi][1][r] + bi;
            const float ff = acc[mi][2][r] + bf_;
            const float oo = acc[mi][3][r] + bo;
            const float c  = tanh_fast(a) * sigf(ii) + sigf(ff) * cprev[off];
            outh[off] = sigf(oo) * tanh_fast(c);
            outc[off] = c;
        }
    }
}

// ---------------- launch ----------------

extern "C" void kernel_launch(void* const* d_in, const int* in_sizes, int n_in,
                              void* d_out, int out_size, void* d_ws, size_t ws_size,
                              hipStream_t stream) {
    const float* top_buf = (const float*)d_in[0];
    const float* s1      = (const float*)d_in[1];
    const float* s2      = (const float*)d_in[2];
    const float* hprev   = (const float*)d_in[3];
    const float* cprev   = (const float*)d_in[4];
    const float* Wb      = (const float*)d_in[5];
    const float* W1      = (const float*)d_in[6];
    const float* W2      = (const float*)d_in[7];
    const float* Wl      = (const float*)d_in[8];
    const float* bl      = (const float*)d_in[9];

    unsigned short* Abf = (unsigned short*)d_ws;                 // 32 MB
    unsigned short* Bt  = Abf + (size_t)4096 * 4096;             // 32 MB

    convert_A<<<16384, 256, 0, stream>>>(top_buf, s1, s2, hprev, Abf);
    convert_B<<<16384, 256, 0, stream>>>(Wb, W1, W2, Wl, Bt);

    dim3 grid(32, 32);
    gemm_lstm<<<grid, 256, 0, stream>>>(Abf, Bt, bl, cprev, (float*)d_out);
}

// Round 3
// 151.183 us; speedup vs baseline: 1.2989x; 1.2989x over previous
//
#include <hip/hip_runtime.h>

// ---------------- helpers ----------------

typedef __bf16 bf16x8 __attribute__((ext_vector_type(8)));
typedef float  f32x4  __attribute__((ext_vector_type(4)));

__device__ __forceinline__ unsigned short f2bf(float x) {
    unsigned int u = __builtin_bit_cast(unsigned int, x);
    u = (u + 0x7fffu + ((u >> 16) & 1u)) >> 16;
    return (unsigned short)u;
}

__device__ __forceinline__ void gl2lds16(const unsigned short* g, unsigned short* l) {
    __builtin_amdgcn_global_load_lds(
        (const __attribute__((address_space(1))) unsigned int*)g,
        (__attribute__((address_space(3))) unsigned int*)l,
        16, 0, 0);
}

__device__ __forceinline__ float sigf(float x) {
    return __builtin_amdgcn_rcpf(1.f + __expf(-x));
}
__device__ __forceinline__ float tanh_fast(float x) {
    return 2.f * __builtin_amdgcn_rcpf(1.f + __expf(-2.f * x)) - 1.f;
}

// ---------------- conversion: activations -> bf16 A [4096][4096] ----------------

__global__ void convert_A(const float* __restrict__ A0, const float* __restrict__ A1,
                          const float* __restrict__ A2, const float* __restrict__ A3,
                          unsigned short* __restrict__ Abf) {
    int idx = blockIdx.x * 256 + threadIdx.x;
    int e0  = idx * 4;
    int b   = e0 >> 12;
    int k   = e0 & 4095;
    const float* S = (k < 1024) ? A0 : (k < 2048) ? A1 : (k < 3072) ? A2 : A3;
    int col = k & 1023;
    const float4 v = *reinterpret_cast<const float4*>(S + (size_t)b * 1024 + col);
    ushort4 o;
    o.x = f2bf(v.x); o.y = f2bf(v.y); o.z = f2bf(v.z); o.w = f2bf(v.w);
    *reinterpret_cast<ushort4*>(Abf + (size_t)b * 4096 + k) = o;
}

// ---------------- conversion: weights -> bf16 B^T with gate-interleave permutation ----
// Bt[p][k] = Wcat[k][ g*1024 + u ],  p = (u>>6)*256 + ((u>>4)&3)*64 + g*16 + (u&15)
// so in the 256x256-tile GEMM epilogue, lane lr of wave wn in block bc holds gates
// a,i,f,o of unit u = bc*64 + wn*16 + lr in its 4 N-fragments.

__global__ void convert_B(const float* __restrict__ Wb, const float* __restrict__ W1,
                          const float* __restrict__ W2, const float* __restrict__ Wl,
                          unsigned short* __restrict__ Bt) {
    __shared__ float t[32][33];
    int tile = blockIdx.x;            // 128 j-tiles x 128 k-tiles
    int jt = tile & 127, kt = tile >> 7;
    int j0 = jt * 32, k0 = kt * 32;
    int ksel = k0 >> 10;
    const float* S = (ksel == 0) ? Wb : (ksel == 1) ? W1 : (ksel == 2) ? W2 : Wl;
    int kloc = k0 & 1023;
    int tx = threadIdx.x & 31, ty = threadIdx.x >> 5;
#pragma unroll
    for (int i = 0; i < 4; ++i) {
        int r = ty + i * 8;
        t[r][tx] = S[(size_t)(kloc + r) * 4096 + j0 + tx];
    }
    __syncthreads();
    int g = j0 >> 10;
    int nbase = j0 & 1023;
#pragma unroll
    for (int i = 0; i < 4; ++i) {
        int jj = ty + i * 8;
        int u  = nbase + jj;
        int p  = (u >> 6) * 256 + ((u >> 4) & 3) * 64 + g * 16 + (u & 15);
        Bt[(size_t)p * 4096 + k0 + tx] = f2bf(t[tx][jj]);
    }
}

// ---------------- 256x256 8-phase GEMM + fused LSTM epilogue ----------------
// A [4096][4096] bf16 row-major, Bt [4096(p)][4096(k)] bf16 row-major (B^T).
// 512 threads = 8 waves (2M x 4N); per wave 128x64 output = acc[8][4] f32x4.
// BK=64; LDS: 2 x (A 256x64 + B 256x64) bf16 = 128 KiB, XOR-swizzled (row&7)<<4.

__global__ __launch_bounds__(512, 2) void gemm_lstm(
        const unsigned short* __restrict__ A,
        const unsigned short* __restrict__ Bt,
        const float* __restrict__ bias,
        const float* __restrict__ cprev,
        float* __restrict__ out) {
    __shared__ unsigned short lds[65536];          // 128 KiB
    // LDS regions via arithmetic (no pointer-array initializers — addrspacecast issue):
    //   A buf b: lds + b*16384        B buf b: lds + 32768 + b*16384
#define ASB(b) (lds + (b) * 16384)
#define BSB(b) (lds + 32768 + (b) * 16384)

    const int tid  = threadIdx.x;
    const int wid  = tid >> 6;
    const int lane = tid & 63;
    const int wm = wid >> 2, wn = wid & 3;         // 2 x 4 wave grid
    const int lr = lane & 15, lq = lane >> 4;
    const int bm = blockIdx.y, bc = blockIdx.x;

    // ---- staging geometry: half-tile = 128 rows x 64 cols = 16 KB; 2 chunks/thread ----
    // LDS byte within half-region: X = j*8192 + wid*1024 + lane*16 (j=0,1)
    // content swizzle: LDS byte X holds global (row = X>>7, colbyte = (X&127) ^ ((row&7)<<4))
    const int X0 = wid * 1024 + lane * 16;                 // j=0 portion, rows 0..63
    const int rs = X0 >> 7;
    const int cs = ((X0 & 127) ^ ((rs & 7) << 4)) >> 1;    // element col
    const unsigned short* Agb = A  + ((size_t)(bm * 256 + rs)) * 4096 + cs;
    const unsigned short* Bgb = Bt + ((size_t)(bc * 256 + rs)) * 4096 + cs;

    // ---- ds_read fragment col offsets (elements), read-side swizzle ----
    const int swz = (lr & 7) << 4;
    const int ca0 = ((lq * 16) ^ swz) >> 1;        // ks=0
    const int ca1 = ((64 + lq * 16) ^ swz) >> 1;   // ks=1

    f32x4 acc[8][4] = {};                          // acc[mi][gate]

#define STAGE_A(b, h, kt) do {                                               \
        unsigned short* _d = ASB(b) + (h) * 8192 + wid * 512;                \
        const unsigned short* _s = Agb + (size_t)((h) * 128) * 4096 + (kt) * 64; \
        gl2lds16(_s, _d);                                                    \
        gl2lds16(_s + 64 * 4096, _d + 4096);                                 \
    } while (0)
#define STAGE_B(b, h, kt) do {                                               \
        unsigned short* _d = BSB(b) + (h) * 8192 + wid * 512;                \
        const unsigned short* _s = Bgb + (size_t)((h) * 128) * 4096 + (kt) * 64; \
        gl2lds16(_s, _d);                                                    \
        gl2lds16(_s + 64 * 4096, _d + 4096);                                 \
    } while (0)
#define LDA(buf, mi, cax) (*reinterpret_cast<const bf16x8*>((buf) + (wm * 128 + (mi) * 16 + lr) * 64 + (cax)))
#define LDB(buf, ni, cax) (*reinterpret_cast<const bf16x8*>((buf) + (wn * 64  + (ni) * 16 + lr) * 64 + (cax)))
#define BARRIER() asm volatile("s_barrier" ::: "memory")
#define MFMA16(P)                                                            \
        __builtin_amdgcn_s_setprio(1);                                       \
        _Pragma("unroll")                                                    \
        for (int m = 0; m < 2; ++m)                                          \
        _Pragma("unroll")                                                    \
        for (int ks = 0; ks < 2; ++ks)                                       \
        _Pragma("unroll")                                                    \
        for (int ni = 0; ni < 4; ++ni)                                       \
            acc[(P)*2 + m][ni] = __builtin_amdgcn_mfma_f32_16x16x32_bf16(    \
                af[m][ks], bfr[ni][ks], acc[(P)*2 + m][ni], 0, 0, 0);        \
        __builtin_amdgcn_s_setprio(0)

    // ---- prologue: tile0 fully + tile1 B halves (12 loads/thread) ----
    STAGE_A(0, 0, 0); STAGE_A(0, 1, 0);
    STAGE_B(0, 0, 0); STAGE_B(0, 1, 0);
    STAGE_B(1, 0, 1); STAGE_B(1, 1, 1);
    asm volatile("s_waitcnt vmcnt(4)" ::: "memory");   // tile0's 8 loads landed
    BARRIER();

    for (int t = 0; t < 64; ++t) {
        const unsigned short* Ac = ASB(t & 1);
        const unsigned short* Bc = BSB(t & 1);
        const int bn  = (t & 1) ^ 1;               // dest buf for A stages (tile t+1)
        const int bb  = t & 1;                     // dest buf for B stages (tile t+2)
        const int ktA = (t < 63) ? t + 1 : 63;     // clamped tail (dead data, never read)
        const int ktB = (t < 62) ? t + 2 : 63;

        bf16x8 bfr[4][2];
        // ---------- phase 0: 8 B-frags + A mi{0,1}; stage A-half0(t+1) ----------
        {
            bf16x8 af[2][2];
#pragma unroll
            for (int ni = 0; ni < 4; ++ni) { bfr[ni][0] = LDB(Bc, ni, ca0); bfr[ni][1] = LDB(Bc, ni, ca1); }
#pragma unroll
            for (int m = 0; m < 2; ++m) { af[m][0] = LDA(Ac, 0 + m, ca0); af[m][1] = LDA(Ac, 0 + m, ca1); }
            STAGE_A(bn, 0, ktA);
            BARRIER();
            MFMA16(0);
            BARRIER();
        }
        // ---------- phase 1: A mi{2,3}; stage A-half1(t+1) ----------
        {
            bf16x8 af[2][2];
#pragma unroll
            for (int m = 0; m < 2; ++m) { af[m][0] = LDA(Ac, 2 + m, ca0); af[m][1] = LDA(Ac, 2 + m, ca1); }
            STAGE_A(bn, 1, ktA);
            BARRIER();
            MFMA16(1);
            BARRIER();
        }
        // ---------- phase 2: A mi{4,5}; stage B-half0(t+2) ----------
        {
            bf16x8 af[2][2];
#pragma unroll
            for (int m = 0; m < 2; ++m) { af[m][0] = LDA(Ac, 4 + m, ca0); af[m][1] = LDA(Ac, 4 + m, ca1); }
            STAGE_B(bb, 0, ktB);
            BARRIER();
            MFMA16(2);
            BARRIER();
        }
        // ---------- phase 3: A mi{6,7}; stage B-half1(t+2); counted vmcnt fence ----------
        {
            bf16x8 af[2][2];
#pragma unroll
            for (int m = 0; m < 2; ++m) { af[m][0] = LDA(Ac, 6 + m, ca0); af[m][1] = LDA(Ac, 6 + m, ca1); }
            STAGE_B(bb, 1, ktB);
            BARRIER();
            MFMA16(3);
            asm volatile("s_waitcnt vmcnt(4)" ::: "memory");   // tile t+1 fully landed
            BARRIER();
        }
    }

    // ---- fused LSTM epilogue: lane lr holds a,i,f,o of unit u in ni=0..3 ----
    const int u = bc * 64 + wn * 16 + lr;
    const float ba  = bias[u];
    const float bi  = bias[1024 + u];
    const float bfv = bias[2048 + u];
    const float bo  = bias[3072 + u];
    float* outh = out;
    float* outc = out + (size_t)4096 * 1024;

#pragma unroll
    for (int mi = 0; mi < 8; ++mi) {
        const int r0 = bm * 256 + wm * 128 + mi * 16 + lq * 4;
#pragma unroll
        for (int r = 0; r < 4; ++r) {
            const size_t off = (size_t)(r0 + r) * 1024 + u;
            const float a  = acc[mi][0][r] + ba;
            const float ii = acc[mi][1][r] + bi;
            const float ff = acc[mi][2][r] + bfv;
            const float oo = acc[mi][3][r] + bo;
            const float c  = tanh_fast(a) * sigf(ii) + sigf(ff) * cprev[off];
            outh[off] = sigf(oo) * tanh_fast(c);
            outc[off] = c;
        }
    }
#undef STAGE_A
#undef STAGE_B
#undef LDA
#undef LDB
#undef BARRIER
#undef MFMA16
#undef ASB
#undef BSB
}

// ---------------- launch ----------------

extern "C" void kernel_launch(void* const* d_in, const int* in_sizes, int n_in,
                              void* d_out, int out_size, void* d_ws, size_t ws_size,
                              hipStream_t stream) {
    const float* top_buf = (const float*)d_in[0];
    const float* s1      = (const float*)d_in[1];
    const float* s2      = (const float*)d_in[2];
    const float* hprev   = (const float*)d_in[3];
    const float* cprev   = (const float*)d_in[4];
    const float* Wb      = (const float*)d_in[5];
    const float* W1      = (const float*)d_in[6];
    const float* W2      = (const float*)d_in[7];
    const float* Wl      = (const float*)d_in[8];
    const float* bl      = (const float*)d_in[9];

    unsigned short* Abf = (unsigned short*)d_ws;                 // 32 MB
    unsigned short* Bt  = Abf + (size_t)4096 * 4096;             // 32 MB

    convert_A<<<16384, 256, 0, stream>>>(top_buf, s1, s2, hprev, Abf);
    convert_B<<<16384, 256, 0, stream>>>(Wb, W1, W2, Wl, Bt);

    dim3 grid(16, 16);
    gemm_lstm<<<grid, 512, 0, stream>>>(Abf, Bt, bl, cprev, (float*)d_out);
}

// Round 4
// 147.081 us; speedup vs baseline: 1.3351x; 1.0279x over previous
//
#include <hip/hip_runtime.h>

// ---------------- helpers ----------------

typedef __bf16 bf16x8 __attribute__((ext_vector_type(8)));
typedef float  f32x4  __attribute__((ext_vector_type(4)));

__device__ __forceinline__ unsigned short f2bf(float x) {
    unsigned int u = __builtin_bit_cast(unsigned int, x);
    u = (u + 0x7fffu + ((u >> 16) & 1u)) >> 16;
    return (unsigned short)u;
}

__device__ __forceinline__ void gl2lds16(const unsigned short* g, unsigned short* l) {
    __builtin_amdgcn_global_load_lds(
        (const __attribute__((address_space(1))) unsigned int*)g,
        (__attribute__((address_space(3))) unsigned int*)l,
        16, 0, 0);
}

__device__ __forceinline__ float sigf(float x) {
    return __builtin_amdgcn_rcpf(1.f + __expf(-x));
}
__device__ __forceinline__ float tanh_fast(float x) {
    return 2.f * __builtin_amdgcn_rcpf(1.f + __expf(-2.f * x)) - 1.f;
}

// ---------------- fused conversion kernel ----------------
// blocks [0,16384): activations -> bf16 A [4096][4096]
//   columns: [0,1024)=top_buf, [1024,2048)=stack1, [2048,3072)=stack2, [3072,4096)=h_prev
// blocks [16384,32768): weights -> bf16 B^T with gate-interleave permutation
//   Bt[p][k] = Wcat[k][ g*1024 + u ],  p = (u>>6)*256 + ((u>>4)&3)*64 + g*16 + (u&15)
//   so in the GEMM epilogue, lane lr of wave wn in block bc holds gates a,i,f,o of
//   unit u = bc*64 + wn*16 + lr in its 4 N-fragments.

__global__ void convert_AB(const float* __restrict__ A0, const float* __restrict__ A1,
                           const float* __restrict__ A2, const float* __restrict__ A3,
                           const float* __restrict__ Wb, const float* __restrict__ W1,
                           const float* __restrict__ W2, const float* __restrict__ Wl,
                           unsigned short* __restrict__ Abf,
                           unsigned short* __restrict__ Bt) {
    __shared__ float t[32][33];
    if (blockIdx.x < 16384) {
        int idx = blockIdx.x * 256 + threadIdx.x;
        int e0  = idx * 4;
        int b   = e0 >> 12;
        int k   = e0 & 4095;
        const float* S = (k < 1024) ? A0 : (k < 2048) ? A1 : (k < 3072) ? A2 : A3;
        int col = k & 1023;
        const float4 v = *reinterpret_cast<const float4*>(S + (size_t)b * 1024 + col);
        ushort4 o;
        o.x = f2bf(v.x); o.y = f2bf(v.y); o.z = f2bf(v.z); o.w = f2bf(v.w);
        *reinterpret_cast<ushort4*>(Abf + (size_t)b * 4096 + k) = o;
    } else {
        int tile = blockIdx.x - 16384;    // 128 j-tiles x 128 k-tiles
        int jt = tile & 127, kt = tile >> 7;
        int j0 = jt * 32, k0 = kt * 32;
        int ksel = k0 >> 10;
        const float* S = (ksel == 0) ? Wb : (ksel == 1) ? W1 : (ksel == 2) ? W2 : Wl;
        int kloc = k0 & 1023;
        int tx = threadIdx.x & 31, ty = threadIdx.x >> 5;
#pragma unroll
        for (int i = 0; i < 4; ++i) {
            int r = ty + i * 8;
            t[r][tx] = S[(size_t)(kloc + r) * 4096 + j0 + tx];
        }
        __syncthreads();
        int g = j0 >> 10;
        int nbase = j0 & 1023;
#pragma unroll
        for (int i = 0; i < 4; ++i) {
            int jj = ty + i * 8;
            int u  = nbase + jj;
            int p  = (u >> 6) * 256 + ((u >> 4) & 3) * 64 + g * 16 + (u & 15);
            Bt[(size_t)p * 4096 + k0 + tx] = f2bf(t[tx][jj]);
        }
    }
}

// ---------------- 256x256 8-phase GEMM + fused LSTM epilogue ----------------
// A [4096][4096] bf16 row-major, Bt [4096(p)][4096(k)] bf16 row-major (B^T).
// 512 threads = 8 waves (2M x 4N); per wave 128x64 output = acc[8][4] f32x4.
// BK=64; LDS: 2 x (A 256x64 + B 256x64) bf16 = 128 KiB, XOR-swizzled (row&7)<<4.
// Barrier discipline per m201 template: builtin s_barrier (no compiler memory
// fence -> compiler may interleave ds_read/global_load_lds with MFMA across
// phase boundaries), bare lgkmcnt(0) pin before each MFMA cluster, single
// memory-clobbered counted vmcnt per K-tile (never drain to 0).

__global__ __launch_bounds__(512, 2) void gemm_lstm(
        const unsigned short* __restrict__ A,
        const unsigned short* __restrict__ Bt,
        const float* __restrict__ bias,
        const float* __restrict__ cprev,
        float* __restrict__ out) {
    __shared__ unsigned short lds[65536];          // 128 KiB
#define ASB(b) (lds + (b) * 16384)
#define BSB(b) (lds + 32768 + (b) * 16384)

    const int tid  = threadIdx.x;
    const int wid  = tid >> 6;
    const int lane = tid & 63;
    const int wm = wid >> 2, wn = wid & 3;         // 2 x 4 wave grid
    const int lr = lane & 15, lq = lane >> 4;
    const int bm = blockIdx.y, bc = blockIdx.x;

    // ---- staging geometry: half-tile = 128 rows x 64 cols = 16 KB; 2 chunks/thread ----
    // LDS byte within half-region: X = j*8192 + wid*1024 + lane*16 (j=0,1)
    // content swizzle: LDS byte X holds global (row = X>>7, colbyte = (X&127) ^ ((row&7)<<4))
    const int X0 = wid * 1024 + lane * 16;                 // j=0 portion, rows 0..63
    const int rs = X0 >> 7;
    const int cs = ((X0 & 127) ^ ((rs & 7) << 4)) >> 1;    // element col
    const unsigned short* Agb = A  + ((size_t)(bm * 256 + rs)) * 4096 + cs;
    const unsigned short* Bgb = Bt + ((size_t)(bc * 256 + rs)) * 4096 + cs;

    // ---- ds_read fragment col offsets (elements), read-side swizzle ----
    const int swz = (lr & 7) << 4;
    const int ca0 = ((lq * 16) ^ swz) >> 1;        // ks=0
    const int ca1 = ((64 + lq * 16) ^ swz) >> 1;   // ks=1

    f32x4 acc[8][4] = {};                          // acc[mi][gate]

#define STAGE_A(b, h, kt) do {                                               \
        unsigned short* _d = ASB(b) + (h) * 8192 + wid * 512;                \
        const unsigned short* _s = Agb + (size_t)((h) * 128) * 4096 + (kt) * 64; \
        gl2lds16(_s, _d);                                                    \
        gl2lds16(_s + 64 * 4096, _d + 4096);                                 \
    } while (0)
#define STAGE_B(b, h, kt) do {                                               \
        unsigned short* _d = BSB(b) + (h) * 8192 + wid * 512;                \
        const unsigned short* _s = Bgb + (size_t)((h) * 128) * 4096 + (kt) * 64; \
        gl2lds16(_s, _d);                                                    \
        gl2lds16(_s + 64 * 4096, _d + 4096);                                 \
    } while (0)
#define LDA(buf, mi, cax) (*reinterpret_cast<const bf16x8*>((buf) + (wm * 128 + (mi) * 16 + lr) * 64 + (cax)))
#define LDB(buf, ni, cax) (*reinterpret_cast<const bf16x8*>((buf) + (wn * 64  + (ni) * 16 + lr) * 64 + (cax)))
#define SBAR() __builtin_amdgcn_s_barrier()
#define LGK0() asm volatile("s_waitcnt lgkmcnt(0)")
#define MFMA16(P)                                                            \
        __builtin_amdgcn_s_setprio(1);                                       \
        _Pragma("unroll")                                                    \
        for (int m = 0; m < 2; ++m)                                          \
        _Pragma("unroll")                                                    \
        for (int ks = 0; ks < 2; ++ks)                                       \
        _Pragma("unroll")                                                    \
        for (int ni = 0; ni < 4; ++ni)                                       \
            acc[(P)*2 + m][ni] = __builtin_amdgcn_mfma_f32_16x16x32_bf16(    \
                af[m][ks], bfr[ni][ks], acc[(P)*2 + m][ni], 0, 0, 0);        \
        __builtin_amdgcn_s_setprio(0)

    // ---- prologue: tile0 fully + tile1 B halves (12 loads/thread) ----
    STAGE_A(0, 0, 0); STAGE_A(0, 1, 0);
    STAGE_B(0, 0, 0); STAGE_B(0, 1, 0);
    STAGE_B(1, 0, 1); STAGE_B(1, 1, 1);
    asm volatile("s_waitcnt vmcnt(4)" ::: "memory");   // tile0's 8 loads landed
    SBAR();

#pragma unroll 2
    for (int t = 0; t < 64; ++t) {
        const unsigned short* Ac = ASB(t & 1);
        const unsigned short* Bc = BSB(t & 1);
        const int bn  = (t & 1) ^ 1;               // dest buf for A stages (tile t+1)
        const int bb  = t & 1;                     // dest buf for B stages (tile t+2)
        const int ktA = (t < 63) ? t + 1 : 63;     // clamped tail (dead data, never read)
        const int ktB = (t < 62) ? t + 2 : 63;

        bf16x8 bfr[4][2];
        // ---------- phase 0: 8 B-frags + A mi{0,1}; stage A-half0(t+1) ----------
        {
            bf16x8 af[2][2];
#pragma unroll
            for (int ni = 0; ni < 4; ++ni) { bfr[ni][0] = LDB(Bc, ni, ca0); bfr[ni][1] = LDB(Bc, ni, ca1); }
#pragma unroll
            for (int m = 0; m < 2; ++m) { af[m][0] = LDA(Ac, 0 + m, ca0); af[m][1] = LDA(Ac, 0 + m, ca1); }
            STAGE_A(bn, 0, ktA);
            SBAR();
            LGK0();
            MFMA16(0);
            SBAR();
        }
        // ---------- phase 1: A mi{2,3}; stage A-half1(t+1) ----------
        {
            bf16x8 af[2][2];
#pragma unroll
            for (int m = 0; m < 2; ++m) { af[m][0] = LDA(Ac, 2 + m, ca0); af[m][1] = LDA(Ac, 2 + m, ca1); }
            STAGE_A(bn, 1, ktA);
            SBAR();
            LGK0();
            MFMA16(1);
            SBAR();
        }
        // ---------- phase 2: A mi{4,5}; stage B-half0(t+2) ----------
        {
            bf16x8 af[2][2];
#pragma unroll
            for (int m = 0; m < 2; ++m) { af[m][0] = LDA(Ac, 4 + m, ca0); af[m][1] = LDA(Ac, 4 + m, ca1); }
            STAGE_B(bb, 0, ktB);
            SBAR();
            LGK0();
            MFMA16(2);
            SBAR();
        }
        // ---------- phase 3: A mi{6,7}; stage B-half1(t+2); counted vmcnt fence ----------
        {
            bf16x8 af[2][2];
#pragma unroll
            for (int m = 0; m < 2; ++m) { af[m][0] = LDA(Ac, 6 + m, ca0); af[m][1] = LDA(Ac, 6 + m, ca1); }
            STAGE_B(bb, 1, ktB);
            SBAR();
            LGK0();
            MFMA16(3);
            asm volatile("s_waitcnt vmcnt(4)" ::: "memory");   // tile t+1 fully landed
            SBAR();
        }
    }

    // ---- fused LSTM epilogue: lane lr holds a,i,f,o of unit u in ni=0..3 ----
    const int u = bc * 64 + wn * 16 + lr;
    const float ba  = bias[u];
    const float bi  = bias[1024 + u];
    const float bfv = bias[2048 + u];
    const float bo  = bias[3072 + u];
    float* outh = out;
    float* outc = out + (size_t)4096 * 1024;

#pragma unroll
    for (int mi = 0; mi < 8; ++mi) {
        const int r0 = bm * 256 + wm * 128 + mi * 16 + lq * 4;
#pragma unroll
        for (int r = 0; r < 4; ++r) {
            const size_t off = (size_t)(r0 + r) * 1024 + u;
            const float a  = acc[mi][0][r] + ba;
            const float ii = acc[mi][1][r] + bi;
            const float ff = acc[mi][2][r] + bfv;
            const float oo = acc[mi][3][r] + bo;
            const float c  = tanh_fast(a) * sigf(ii) + sigf(ff) * cprev[off];
            outh[off] = sigf(oo) * tanh_fast(c);
            outc[off] = c;
        }
    }
#undef STAGE_A
#undef STAGE_B
#undef LDA
#undef LDB
#undef SBAR
#undef LGK0
#undef MFMA16
#undef ASB
#undef BSB
}

// ---------------- launch ----------------

extern "C" void kernel_launch(void* const* d_in, const int* in_sizes, int n_in,
                              void* d_out, int out_size, void* d_ws, size_t ws_size,
                              hipStream_t stream) {
    const float* top_buf = (const float*)d_in[0];
    const float* s1      = (const float*)d_in[1];
    const float* s2      = (const float*)d_in[2];
    const float* hprev   = (const float*)d_in[3];
    const float* cprev   = (const float*)d_in[4];
    const float* Wb      = (const float*)d_in[5];
    const float* W1      = (const float*)d_in[6];
    const float* W2      = (const float*)d_in[7];
    const float* Wl      = (const float*)d_in[8];
    const float* bl      = (const float*)d_in[9];

    unsigned short* Abf = (unsigned short*)d_ws;                 // 32 MB
    unsigned short* Bt  = Abf + (size_t)4096 * 4096;             // 32 MB

    convert_AB<<<32768, 256, 0, stream>>>(top_buf, s1, s2, hprev,
                                          Wb, W1, W2, Wl, Abf, Bt);

    dim3 grid(16, 16);
    gemm_lstm<<<grid, 512, 0, stream>>>(Abf, Bt, bl, cprev, (float*)d_out);
}